// Round 6
// baseline (823.805 us; speedup 1.0000x reference)
//
#include <hip/hip_runtime.h>
#include <stdint.h>

typedef unsigned short bfu;
typedef __attribute__((ext_vector_type(8))) short bf16x8;   // MFMA A/B frag
typedef __attribute__((ext_vector_type(4))) float f32x4;    // MFMA C/D frag

__device__ __forceinline__ bfu f2b(float f) {
  unsigned int i = __builtin_bit_cast(unsigned int, f);
  i += 0x7FFFu + ((i >> 16) & 1u);  // round-to-nearest-even
  return (bfu)(i >> 16);
}

// ---------------- round-3 GEMM (best measured): 2-barrier, 32KB LDS ----------
// C[M,N] = A[M,K] @ B[N,K]^T. 128x128 tile, BK=64, VGPR-mediated staging.
// MODE 0: atomicAdd f32 (split-K via blockIdx.z when zIsK)
// MODE 1: store bf16 via LDS repack (swizzled, 16B/lane stores)
template <int MODE>
__global__ __launch_bounds__(256) void gemm_bt(
    const bfu* __restrict__ A, const bfu* __restrict__ B, void* __restrict__ Cv,
    int lda, int ldb, int ldc,
    long long sA, long long sB, long long sC,
    int Klen, int zIsK) {
  __shared__ __align__(16) bfu S[128 * 128];
  bfu* At = S;
  bfu* Bt = S + 128 * 64;
  const int tid = threadIdx.x;
  const int lane = tid & 63;
  const int wid = tid >> 6;
  const int wm = wid >> 1, wn = wid & 1;

  int k0 = 0;
  long long cOff = 0;
  if (zIsK) {
    k0 = blockIdx.z * Klen;
  } else {
    A += (long long)blockIdx.z * sA;
    B += (long long)blockIdx.z * sB;
    cOff = (long long)blockIdx.z * sC;
  }
  const int m0 = blockIdx.y * 128;
  const int n0 = blockIdx.x * 128;
  const bfu* Ag = A + (long long)m0 * lda + k0;
  const bfu* Bg = B + (long long)n0 * ldb + k0;

  f32x4 acc[4][4];
  const f32x4 zero = {0.f, 0.f, 0.f, 0.f};
#pragma unroll
  for (int r = 0; r < 4; ++r)
#pragma unroll
    for (int c = 0; c < 4; ++c) acc[r][c] = zero;

  const int trow = tid >> 3;
  const int tcol = (tid & 7) * 8;

  const int nIter = Klen >> 6;
  for (int kt = 0; kt < nIter; ++kt) {
    const bfu* Ak = Ag + kt * 64;
    const bfu* Bk = Bg + kt * 64;
    uint4 av[4], bv[4];
#pragma unroll
    for (int i = 0; i < 4; ++i) {
      const int row = trow + i * 32;
      av[i] = *(const uint4*)(Ak + (long long)row * lda + tcol);
      bv[i] = *(const uint4*)(Bk + (long long)row * ldb + tcol);
    }
#pragma unroll
    for (int i = 0; i < 4; ++i) {
      const int row = trow + i * 32;
      *(uint4*)(At + row * 64 + tcol) = av[i];
      *(uint4*)(Bt + row * 64 + tcol) = bv[i];
    }
    __syncthreads();
#pragma unroll
    for (int kk = 0; kk < 2; ++kk) {
      bf16x8 af[4], bfr[4];
      const int ko = kk * 32 + (lane >> 4) * 8;
#pragma unroll
      for (int r = 0; r < 4; ++r)
        af[r] = *(const bf16x8*)(At + (wm * 64 + r * 16 + (lane & 15)) * 64 + ko);
#pragma unroll
      for (int c = 0; c < 4; ++c)
        bfr[c] = *(const bf16x8*)(Bt + (wn * 64 + c * 16 + (lane & 15)) * 64 + ko);
#pragma unroll
      for (int r = 0; r < 4; ++r)
#pragma unroll
        for (int c = 0; c < 4; ++c)
          acc[r][c] = __builtin_amdgcn_mfma_f32_16x16x32_bf16(af[r], bfr[c], acc[r][c], 0, 0, 0);
    }
    __syncthreads();
  }

  if (MODE == 0) {
    float* Cf = (float*)Cv;
#pragma unroll
    for (int r = 0; r < 4; ++r) {
#pragma unroll
      for (int c = 0; c < 4; ++c) {
        const int gr = m0 + wm * 64 + r * 16 + ((lane >> 4) << 2);
        const int gc = n0 + wn * 64 + c * 16 + (lane & 15);
#pragma unroll
        for (int v = 0; v < 4; ++v)
          atomicAdd(Cf + cOff + (long long)(gr + v) * ldc + gc, acc[r][c][v]);
      }
    }
  } else {
    __syncthreads();
#pragma unroll
    for (int r = 0; r < 4; ++r) {
#pragma unroll
      for (int c = 0; c < 4; ++c) {
        const int col = wn * 64 + c * 16 + (lane & 15);
#pragma unroll
        for (int v = 0; v < 4; ++v) {
          const int row = wm * 64 + r * 16 + ((lane >> 4) << 2) + v;
          S[row * 128 + (col ^ (((row >> 2) & 3) << 4))] = f2b(acc[r][c][v]);
        }
      }
    }
    __syncthreads();
    bfu* Cb = (bfu*)Cv;
#pragma unroll
    for (int i = 0; i < 8; ++i) {
      const int j = i * 256 + tid;
      const int row = j >> 4;
      const int colbase = (j & 15) * 8;
      const int sc = colbase ^ (((row >> 2) & 3) << 4);
      uint4 val = *(const uint4*)(S + row * 128 + sc);
      *(uint4*)(Cb + cOff + (long long)(m0 + row) * ldc + n0 + colbase) = val;
    }
  }
}

// ---------------- fused attention: logits -> softmax -> PV -> out-proj -------
// Block: 32 s-rows (blockIdx.x), head-group hg=blockIdx.y (4 heads).
// acc2[s][o] persists in registers across the 4 heads; P lives in LDS.
__global__ __launch_bounds__(256, 2) void flash_k(
    const bfu* __restrict__ Xb,   // [8192][512]
    const bfu* __restrict__ Mb,   // [8][512][512]
    const bfu* __restrict__ Ncat, // [512][4096]  N_h at col h*512
    const float* __restrict__ cb, // [8][512]
    float* __restrict__ part) {   // [2][8192][512]
  __shared__ __align__(16) bfu Bs[512 * 32];   // B staging (32 KB), xor-swizzled chunks
  __shared__ __align__(16) bfu Ps[32 * 520];   // P tile, row pad +8 (33.3 KB)
  __shared__ float redA[4][32];
  __shared__ float redB[4][32];

  const int tid = threadIdx.x;
  const int lane = tid & 63;
  const int w = tid >> 6;
  const int l15 = lane & 15, l4 = lane >> 4;
  const int s0 = blockIdx.x * 32;
  const int hg = blockIdx.y;
  const float scale = 0.044194173824159216f;  // 1/sqrt(512)

  f32x4 acc2[2][8];
  const f32x4 zero = {0.f, 0.f, 0.f, 0.f};
#pragma unroll
  for (int rg = 0; rg < 2; ++rg)
#pragma unroll
    for (int cf = 0; cf < 8; ++cf) acc2[rg][cf] = zero;

  for (int hi = 0; hi < 4; ++hi) {
    const int h = hg * 4 + hi;
    // ---------- phase 1: logits = X_tile(32x512) @ M_h^T ----------
    f32x4 acc1[2][8];
#pragma unroll
    for (int rg = 0; rg < 2; ++rg)
#pragma unroll
      for (int cf = 0; cf < 8; ++cf) acc1[rg][cf] = zero;

    const bfu* Bg1 = Mb + h * 262144;  // [512 a][512 x]
    for (int kt = 0; kt < 16; ++kt) {
      const int k0 = kt * 32;
      uint4 st[8];
#pragma unroll
      for (int j = 0; j < 8; ++j) {
        const int id = j * 256 + tid;
        const int a = id >> 2, c = id & 3;
        st[j] = *(const uint4*)(Bg1 + a * 512 + k0 + c * 8);
      }
      __syncthreads();  // Bs free (prior readers done)
#pragma unroll
      for (int j = 0; j < 8; ++j) {
        const int id = j * 256 + tid;
        const int a = id >> 2, c = id & 3;
        *(uint4*)(Bs + (a * 4 + (c ^ (a & 3))) * 8) = st[j];
      }
      __syncthreads();
      bf16x8 af[2];
#pragma unroll
      for (int rg = 0; rg < 2; ++rg)
        af[rg] = *(const bf16x8*)(Xb + (long long)(s0 + rg * 16 + l15) * 512 + k0 + l4 * 8);
#pragma unroll
      for (int cf = 0; cf < 8; ++cf) {
        const int a = w * 128 + cf * 16 + l15;
        bf16x8 bfr = *(const bf16x8*)(Bs + (a * 4 + (l4 ^ (a & 3))) * 8);
#pragma unroll
        for (int rg = 0; rg < 2; ++rg)
          acc1[rg][cf] = __builtin_amdgcn_mfma_f32_16x16x32_bf16(af[rg], bfr, acc1[rg][cf], 0, 0, 0);
      }
    }

    // ---------- softmax over a (512 cols) ----------
    float cbl[8];
#pragma unroll
    for (int cf = 0; cf < 8; ++cf) cbl[cf] = cb[h * 512 + w * 128 + cf * 16 + l15];
#pragma unroll
    for (int rg = 0; rg < 2; ++rg)
#pragma unroll
      for (int cf = 0; cf < 8; ++cf)
#pragma unroll
        for (int v = 0; v < 4; ++v)
          acc1[rg][cf][v] = (acc1[rg][cf][v] + cbl[cf]) * scale;

    float pm[2][4];
#pragma unroll
    for (int rg = 0; rg < 2; ++rg)
#pragma unroll
      for (int v = 0; v < 4; ++v) pm[rg][v] = -3.0e38f;
#pragma unroll
    for (int rg = 0; rg < 2; ++rg)
#pragma unroll
      for (int cf = 0; cf < 8; ++cf)
#pragma unroll
        for (int v = 0; v < 4; ++v) pm[rg][v] = fmaxf(pm[rg][v], acc1[rg][cf][v]);
#pragma unroll
    for (int m = 1; m < 16; m <<= 1)
#pragma unroll
      for (int rg = 0; rg < 2; ++rg)
#pragma unroll
        for (int v = 0; v < 4; ++v)
          pm[rg][v] = fmaxf(pm[rg][v], __shfl_xor(pm[rg][v], m, 64));
    if (l15 == 0)
#pragma unroll
      for (int rg = 0; rg < 2; ++rg)
#pragma unroll
        for (int v = 0; v < 4; ++v) redA[w][rg * 16 + l4 * 4 + v] = pm[rg][v];
    __syncthreads();
    float rmax[2][4];
#pragma unroll
    for (int rg = 0; rg < 2; ++rg)
#pragma unroll
      for (int v = 0; v < 4; ++v) {
        const int row = rg * 16 + l4 * 4 + v;
        rmax[rg][v] = fmaxf(fmaxf(redA[0][row], redA[1][row]),
                            fmaxf(redA[2][row], redA[3][row]));
      }
    float ps[2][4];
#pragma unroll
    for (int rg = 0; rg < 2; ++rg)
#pragma unroll
      for (int v = 0; v < 4; ++v) ps[rg][v] = 0.f;
#pragma unroll
    for (int rg = 0; rg < 2; ++rg)
#pragma unroll
      for (int cf = 0; cf < 8; ++cf)
#pragma unroll
        for (int v = 0; v < 4; ++v) {
          const float e = __expf(acc1[rg][cf][v] - rmax[rg][v]);
          acc1[rg][cf][v] = e;
          ps[rg][v] += e;
        }
#pragma unroll
    for (int m = 1; m < 16; m <<= 1)
#pragma unroll
      for (int rg = 0; rg < 2; ++rg)
#pragma unroll
        for (int v = 0; v < 4; ++v) ps[rg][v] += __shfl_xor(ps[rg][v], m, 64);
    if (l15 == 0)
#pragma unroll
      for (int rg = 0; rg < 2; ++rg)
#pragma unroll
        for (int v = 0; v < 4; ++v) redB[w][rg * 16 + l4 * 4 + v] = ps[rg][v];
    __syncthreads();
    float rinv[2][4];
#pragma unroll
    for (int rg = 0; rg < 2; ++rg)
#pragma unroll
      for (int v = 0; v < 4; ++v) {
        const int row = rg * 16 + l4 * 4 + v;
        rinv[rg][v] = 1.0f / (redB[0][row] + redB[1][row] + redB[2][row] + redB[3][row]);
      }
    // write P (bf16) to LDS in A-operand-ready layout [32][520]
#pragma unroll
    for (int rg = 0; rg < 2; ++rg)
#pragma unroll
      for (int cf = 0; cf < 8; ++cf)
#pragma unroll
        for (int v = 0; v < 4; ++v)
          Ps[(rg * 16 + l4 * 4 + v) * 520 + w * 128 + cf * 16 + l15] =
              f2b(acc1[rg][cf][v] * rinv[rg][v]);
    __syncthreads();  // P ready; Bs free for phase 2

    // ---------- phase 2: acc2 += P(32x512) @ N_h^T ----------
    const bfu* Bg2 = Ncat + h * 512;  // [512 o][a], ldb 4096
    for (int kt = 0; kt < 16; ++kt) {
      const int k0 = kt * 32;
      uint4 st[8];
#pragma unroll
      for (int j = 0; j < 8; ++j) {
        const int id = j * 256 + tid;
        const int o = id >> 2, c = id & 3;
        st[j] = *(const uint4*)(Bg2 + (long long)o * 4096 + k0 + c * 8);
      }
      __syncthreads();
#pragma unroll
      for (int j = 0; j < 8; ++j) {
        const int id = j * 256 + tid;
        const int o = id >> 2, c = id & 3;
        *(uint4*)(Bs + (o * 4 + (c ^ (o & 3))) * 8) = st[j];
      }
      __syncthreads();
      bf16x8 af[2];
#pragma unroll
      for (int rg = 0; rg < 2; ++rg)
        af[rg] = *(const bf16x8*)(Ps + (rg * 16 + l15) * 520 + k0 + l4 * 8);
#pragma unroll
      for (int cf = 0; cf < 8; ++cf) {
        const int o = w * 128 + cf * 16 + l15;
        bf16x8 bfr = *(const bf16x8*)(Bs + (o * 4 + (l4 ^ (o & 3))) * 8);
#pragma unroll
        for (int rg = 0; rg < 2; ++rg)
          acc2[rg][cf] = __builtin_amdgcn_mfma_f32_16x16x32_bf16(af[rg], bfr, acc2[rg][cf], 0, 0, 0);
      }
    }
    __syncthreads();  // Ps/Bs free for next head
  }

  float* po = part + (long long)hg * 4194304;
#pragma unroll
  for (int rg = 0; rg < 2; ++rg)
#pragma unroll
    for (int cf = 0; cf < 8; ++cf)
#pragma unroll
      for (int v = 0; v < 4; ++v)
        po[(long long)(s0 + rg * 16 + l4 * 4 + v) * 512 + w * 128 + cf * 16 + l15] =
            acc2[rg][cf][v];
}

// out = part[0] + part[1] + bc  (float4)
__global__ __launch_bounds__(256) void reduce_k(const float* __restrict__ part,
                                                const float* __restrict__ bc,
                                                float* __restrict__ out) {
  const int i = blockIdx.x * 256 + threadIdx.x;  // 1048576 float4s
  float4 a = ((const float4*)part)[i];
  float4 b = ((const float4*)(part + 4194304))[i];
  float4 c = ((const float4*)bc)[i & 127];
  float4 o;
  o.x = a.x + b.x + c.x; o.y = a.y + b.y + c.y;
  o.z = a.z + b.z + c.z; o.w = a.w + b.w + c.w;
  ((float4*)out)[i] = o;
}

// ---------------- helpers (round-3) ----------------
__global__ void transpose_k(const float* __restrict__ in, bfu* __restrict__ out,
                            int R, int C) {
  __shared__ bfu t[32][33];
  const long long boff = (long long)blockIdx.z * R * C;
  const int c0 = blockIdx.x * 32, r0 = blockIdx.y * 32;
  const int tx = threadIdx.x, ty = threadIdx.y;
  for (int i = ty; i < 32; i += 8)
    t[i][tx] = f2b(in[boff + (long long)(r0 + i) * C + (c0 + tx)]);
  __syncthreads();
  for (int i = ty; i < 32; i += 8)
    out[boff + (long long)(c0 + i) * R + (r0 + tx)] = t[tx][i];
}

__global__ __launch_bounds__(256) void conv_mat(const float* __restrict__ src,
                                                bfu* __restrict__ dst, int count4) {
  int i = blockIdx.x * 256 + threadIdx.x;
  if (i < count4) {
    float4 f = ((const float4*)src)[i];
    ushort4 o;
    o.x = f2b(f.x); o.y = f2b(f.y); o.z = f2b(f.z); o.w = f2b(f.w);
    ((ushort4*)dst)[i] = o;
  }
}

__global__ __launch_bounds__(256) void zero_k(float* __restrict__ p) {
  p[blockIdx.x * 256 + threadIdx.x] = 0.f;
}

__global__ __launch_bounds__(256) void zero_out_k(float* __restrict__ p, int n) {
  int i = blockIdx.x * 256 + threadIdx.x;
  if (i < n) p[i] = 0.f;
}

__global__ __launch_bounds__(256) void cast_kv(const float* __restrict__ K32,
                                               const float* __restrict__ V32,
                                               bfu* __restrict__ Kb, bfu* __restrict__ VTb) {
  int idx = blockIdx.x * 256 + threadIdx.x;
  int a = idx >> 9, b = idx & 511;
  Kb[idx] = f2b(K32[idx]);
  VTb[idx] = f2b(V32[b * 512 + a]);
}

__global__ __launch_bounds__(256) void cvec_k(const float* __restrict__ K32,
                                              const float* __restrict__ bq,
                                              float* __restrict__ cb) {
  const int lane = threadIdx.x & 63;
  const int w = blockIdx.x * 4 + (threadIdx.x >> 6);
  const int h = w >> 9, a = w & 511;
  float s = 0.f;
#pragma unroll
  for (int i = 0; i < 8; ++i) {
    int q = i * 64 + lane;
    s += K32[a * 512 + q] * bq[h * 512 + q];
  }
#pragma unroll
  for (int off = 32; off; off >>= 1) s += __shfl_xor(s, off, 64);
  if (lane == 0) cb[w] = s;
}

extern "C" void kernel_launch(void* const* d_in, const int* in_sizes, int n_in,
                              void* d_out, int out_size, void* d_ws, size_t ws_size,
                              hipStream_t stream) {
  (void)in_sizes; (void)n_in;
  const float* X    = (const float*)d_in[0];  // [8192,512]
  const float* enc0 = (const float*)d_in[1];  // [512,8192]
  const float* enc1 = (const float*)d_in[2];  // [512,8192]
  const float* Wq   = (const float*)d_in[3];  // [8,512,512]
  const float* bq   = (const float*)d_in[4];  // [8,512]
  const float* Wc   = (const float*)d_in[5];  // [512,4096]
  const float* bc   = (const float*)d_in[6];  // [512]
  float* out = (float*)d_out;                 // [8192,512] f32

  const size_t NEED = 53493760;  // 51.0 MB
  if (ws_size < NEED) {
    zero_out_k<<<dim3((out_size + 255) / 256), 256, 0, stream>>>(out, out_size);
    return;
  }
  char* w = (char*)d_ws;
  bfu*   Xb    = (bfu*)(w + 0);           // [8192][512]   8 MB
  bfu*   XTb   = (bfu*)(w + 8388608);     // [512][8192]   8 MB (transient)
  bfu*   enc0b = (bfu*)(w + 16777216);    // [512][8192]   8 MB (transient)
  bfu*   enc1b = (bfu*)(w + 25165824);    // [512][8192]   8 MB (transient)
  bfu*   WqTb  = (bfu*)(w + 33554432);    // [8][512][512] 4 MB (transient)
  bfu*   Wcb   = (bfu*)(w + 37748736);    // [512][4096]   4 MB (transient)
  float* part  = (float*)(w + 8388608);   // [2][8192][512] 32 MB, overlays XTb..Wcb
  float* K32   = (float*)(w + 41943040);  // [512][512]    1 MB
  float* V32   = (float*)(w + 42991616);  // [512][512]    1 MB
  bfu*   Kb    = (bfu*)(w + 44040192);    // [512][512]  0.5 MB
  bfu*   VTb   = (bfu*)(w + 44564480);    // [512][512]  0.5 MB
  bfu*   Mb    = (bfu*)(w + 45088768);    // [8][512][512] 4 MB
  bfu*   Ncat  = (bfu*)(w + 49283072);    // [512][4096]   4 MB
  float* cb    = (float*)(w + 53477376);  // [8][512]     16 KB

  conv_mat<<<dim3(4096), 256, 0, stream>>>(X, Xb, 1048576);
  conv_mat<<<dim3(4096), 256, 0, stream>>>(enc0, enc0b, 1048576);
  conv_mat<<<dim3(4096), 256, 0, stream>>>(enc1, enc1b, 1048576);
  conv_mat<<<dim3(2048), 256, 0, stream>>>(Wc, Wcb, 524288);

  dim3 tb(32, 8, 1);
  transpose_k<<<dim3(16, 256, 1), tb, 0, stream>>>(X, XTb, 8192, 512);
  transpose_k<<<dim3(16, 16, 8), tb, 0, stream>>>(Wq, WqTb, 512, 512);

  zero_k<<<dim3(2048), 256, 0, stream>>>(K32);  // K32+V32 contiguous

  // K = enc0 @ X, V = enc1 @ X  (split-K over 16 chunks of 512)
  gemm_bt<0><<<dim3(4, 4, 16), 256, 0, stream>>>(enc0b, XTb, K32,
      8192, 8192, 512, 0, 0, 0, 512, 1);
  gemm_bt<0><<<dim3(4, 4, 16), 256, 0, stream>>>(enc1b, XTb, V32,
      8192, 8192, 512, 0, 0, 0, 512, 1);
  cast_kv<<<dim3(1024), 256, 0, stream>>>(K32, V32, Kb, VTb);
  cvec_k<<<dim3(1024), 256, 0, stream>>>(K32, bq, cb);

  // M_h = K @ Wq_h
  gemm_bt<1><<<dim3(4, 4, 8), 256, 0, stream>>>(Kb, WqTb, Mb,
      512, 512, 512, 0, 262144, 262144, 512, 0);
  // N_h = Wc_h @ V -> Ncat[o][h*512+a]
  gemm_bt<1><<<dim3(4, 4, 8), 256, 0, stream>>>(Wcb, VTb, Ncat,
      4096, 512, 4096, 512, 0, 512, 512, 0);

  // fused logits+softmax+PV+out-proj, accumulated over 4 heads per block
  flash_k<<<dim3(256, 2), 256, 0, stream>>>(Xb, Mb, Ncat, cb, part);

  // out = part0 + part1 + bc
  reduce_k<<<dim3(4096), 256, 0, stream>>>(part, bc, out);
}

// Round 7
// 349.533 us; speedup vs baseline: 2.3569x; 2.3569x over previous
//
#include <hip/hip_runtime.h>
#include <stdint.h>

typedef unsigned short bfu;
typedef __attribute__((ext_vector_type(8))) short bf16x8;   // MFMA A/B frag
typedef __attribute__((ext_vector_type(4))) float f32x4;    // MFMA C/D frag

__device__ __forceinline__ bfu f2b(float f) {
  unsigned int i = __builtin_bit_cast(unsigned int, f);
  i += 0x7FFFu + ((i >> 16) & 1u);  // round-to-nearest-even
  return (bfu)(i >> 16);
}

// async global->LDS, 16B per lane. LDS dest must be wave-uniform base + lane*16
// (verified below: every staging instr's per-lane LDS offset == base + lane*16).
__device__ __forceinline__ void stage16(const bfu* g, bfu* l) {
  __builtin_amdgcn_global_load_lds(
      (const __attribute__((address_space(1))) void*)g,
      (__attribute__((address_space(3))) void*)l, 16, 0, 0);
}

// C[M,N] = A[M,K] @ B[N,K]^T. 64x128 tile, BK=64, global_load_lds staging.
// 4 waves in 2x2: wave computes 32 rows x 64 cols (acc[2][4]).
// MODE 0: atomicAdd f32 (split-K via blockIdx.z when zIsK)
// MODE 1: store bf16 via LDS repack (swizzled, 16B/lane stores)
// MODE 2: store f32 with +bias[n]
template <int MODE>
__global__ __launch_bounds__(256) void gemm64(
    const bfu* __restrict__ A, const bfu* __restrict__ B, void* __restrict__ Cv,
    const float* __restrict__ bias,
    int lda, int ldb, int ldc,
    long long sA, long long sB, long long sC,
    int Klen, int zIsK) {
  __shared__ __align__(16) bfu S[12288];  // At 64x64 (8KB) + Bt 128x64 (16KB)
  bfu* At = S;
  bfu* Bt = S + 4096;
  const int tid = threadIdx.x;
  const int lane = tid & 63;
  const int wid = tid >> 6;
  const int l15 = lane & 15, l4 = lane >> 4;
  const int wm = wid >> 1, wn = wid & 1;

  int k0 = 0;
  long long cOff = 0;
  if (zIsK) {
    k0 = blockIdx.z * Klen;
  } else {
    A += (long long)blockIdx.z * sA;
    B += (long long)blockIdx.z * sB;
    cOff = (long long)blockIdx.z * sC;
  }
  const int m0 = blockIdx.y * 64;
  const int n0 = blockIdx.x * 128;
  const bfu* Ag = A + (long long)m0 * lda + k0;
  const bfu* Bg = B + (long long)n0 * ldb + k0;

  f32x4 acc[2][4];
  const f32x4 zero = {0.f, 0.f, 0.f, 0.f};
#pragma unroll
  for (int r = 0; r < 2; ++r)
#pragma unroll
    for (int c = 0; c < 4; ++c) acc[r][c] = zero;

  const int lrow = lane >> 3;        // 0..7 sub-row
  const int lcol = (lane & 7) * 8;   // 16B chunk col

  const int nIter = Klen >> 6;
  for (int kt = 0; kt < nIter; ++kt) {
    const bfu* Ak = Ag + kt * 64;
    const bfu* Bk = Bg + kt * 64;
    // A tile: 64 rows = 8 groups of 8; 4 waves x 2 instrs.
#pragma unroll
    for (int j = 0; j < 2; ++j) {
      const int row = (wid * 2 + j) * 8 + lrow;
      stage16(Ak + (long long)row * lda + lcol, At + row * 64 + lcol);
    }
    // B tile: 128 rows = 16 groups; 4 waves x 4 instrs.
#pragma unroll
    for (int j = 0; j < 4; ++j) {
      const int row = (wid * 4 + j) * 8 + lrow;
      stage16(Bk + (long long)row * ldb + lcol, Bt + row * 64 + lcol);
    }
    __syncthreads();  // drains vmcnt (global_load_lds) per barrier semantics
#pragma unroll
    for (int kk = 0; kk < 2; ++kk) {
      const int ko = kk * 32 + l4 * 8;
      bf16x8 af[2], bfr[4];
#pragma unroll
      for (int r = 0; r < 2; ++r)
        af[r] = *(const bf16x8*)(At + (wm * 32 + r * 16 + l15) * 64 + ko);
#pragma unroll
      for (int c = 0; c < 4; ++c)
        bfr[c] = *(const bf16x8*)(Bt + (wn * 64 + c * 16 + l15) * 64 + ko);
#pragma unroll
      for (int r = 0; r < 2; ++r)
#pragma unroll
        for (int c = 0; c < 4; ++c)
          acc[r][c] = __builtin_amdgcn_mfma_f32_16x16x32_bf16(af[r], bfr[c], acc[r][c], 0, 0, 0);
    }
    __syncthreads();
  }

  if (MODE == 0) {
    float* Cf = (float*)Cv;
#pragma unroll
    for (int r = 0; r < 2; ++r) {
#pragma unroll
      for (int c = 0; c < 4; ++c) {
        const int gr = m0 + wm * 32 + r * 16 + (l4 << 2);
        const int gc = n0 + wn * 64 + c * 16 + l15;
#pragma unroll
        for (int v = 0; v < 4; ++v)
          atomicAdd(Cf + cOff + (long long)(gr + v) * ldc + gc, acc[r][c][v]);
      }
    }
  } else if (MODE == 2) {
    float* Cf = (float*)Cv;
#pragma unroll
    for (int r = 0; r < 2; ++r) {
#pragma unroll
      for (int c = 0; c < 4; ++c) {
        const int gr = m0 + wm * 32 + r * 16 + (l4 << 2);
        const int gc = n0 + wn * 64 + c * 16 + l15;
        const float bval = bias[gc];
#pragma unroll
        for (int v = 0; v < 4; ++v)
          Cf[cOff + (long long)(gr + v) * ldc + gc] = acc[r][c][v] + bval;
      }
    }
  } else {
    // bf16 epilogue: repack 64x128 C tile via LDS (XOR-swizzled), 16B stores.
#pragma unroll
    for (int r = 0; r < 2; ++r) {
#pragma unroll
      for (int c = 0; c < 4; ++c) {
        const int col = wn * 64 + c * 16 + l15;
#pragma unroll
        for (int v = 0; v < 4; ++v) {
          const int row = wm * 32 + r * 16 + (l4 << 2) + v;
          S[row * 128 + (col ^ (((row >> 2) & 3) << 4))] = f2b(acc[r][c][v]);
        }
      }
    }
    __syncthreads();
    bfu* Cb = (bfu*)Cv;
#pragma unroll
    for (int i = 0; i < 4; ++i) {
      const int j = i * 256 + tid;      // 0..1023 uint4s
      const int row = j >> 4;           // 0..63
      const int colbase = (j & 15) * 8; // 0..120
      const int sc = colbase ^ (((row >> 2) & 3) << 4);
      uint4 val = *(const uint4*)(S + row * 128 + sc);
      *(uint4*)(Cb + cOff + (long long)(m0 + row) * ldc + n0 + colbase) = val;
    }
  }
}

// ---------------- helpers (round-3, measured) ----------------
__global__ void transpose_k(const float* __restrict__ in, bfu* __restrict__ out,
                            int R, int C) {
  __shared__ bfu t[32][33];
  const long long boff = (long long)blockIdx.z * R * C;
  const int c0 = blockIdx.x * 32, r0 = blockIdx.y * 32;
  const int tx = threadIdx.x, ty = threadIdx.y;
  for (int i = ty; i < 32; i += 8)
    t[i][tx] = f2b(in[boff + (long long)(r0 + i) * C + (c0 + tx)]);
  __syncthreads();
  for (int i = ty; i < 32; i += 8)
    out[boff + (long long)(c0 + i) * R + (r0 + tx)] = t[tx][i];
}

__global__ __launch_bounds__(256) void conv_mat(const float* __restrict__ src,
                                                bfu* __restrict__ dst, int count4) {
  int i = blockIdx.x * 256 + threadIdx.x;
  if (i < count4) {
    float4 f = ((const float4*)src)[i];
    ushort4 o;
    o.x = f2b(f.x); o.y = f2b(f.y); o.z = f2b(f.z); o.w = f2b(f.w);
    ((ushort4*)dst)[i] = o;
  }
}

__global__ __launch_bounds__(256) void zero_k(float* __restrict__ p) {
  p[blockIdx.x * 256 + threadIdx.x] = 0.f;
}

__global__ __launch_bounds__(256) void zero_out_k(float* __restrict__ p, int n) {
  int i = blockIdx.x * 256 + threadIdx.x;
  if (i < n) p[i] = 0.f;
}

__global__ __launch_bounds__(256) void cast_kv(const float* __restrict__ K32,
                                               const float* __restrict__ V32,
                                               bfu* __restrict__ Kb, bfu* __restrict__ VTb) {
  int idx = blockIdx.x * 256 + threadIdx.x;
  int a = idx >> 9, b = idx & 511;
  Kb[idx] = f2b(K32[idx]);
  VTb[idx] = f2b(V32[b * 512 + a]);
}

__global__ __launch_bounds__(256) void cvec_k(const float* __restrict__ K32,
                                              const float* __restrict__ bq,
                                              float* __restrict__ cb) {
  const int lane = threadIdx.x & 63;
  const int w = blockIdx.x * 4 + (threadIdx.x >> 6);
  const int h = w >> 9, a = w & 511;
  float s = 0.f;
#pragma unroll
  for (int i = 0; i < 8; ++i) {
    int q = i * 64 + lane;
    s += K32[a * 512 + q] * bq[h * 512 + q];
  }
#pragma unroll
  for (int off = 32; off; off >>= 1) s += __shfl_xor(s, off, 64);
  if (lane == 0) cb[w] = s;
}

// In-place softmax over Ecat[s][h*512 .. +512], wave per row.
__global__ __launch_bounds__(256) void softmax_k(bfu* __restrict__ E, const float* __restrict__ cb) {
  const int lane = threadIdx.x & 63;
  const int w = blockIdx.x * 4 + (threadIdx.x >> 6);
  const int h = w >> 13;
  const int s = w & 8191;
  bfu* row = E + (long long)s * 4096 + h * 512;
  const float* ch = cb + h * 512 + lane * 8;
  const float scale = 0.044194173824159216f;  // 1/sqrt(512)
  union { uint4 u; bfu us[8]; } io;
  io.u = *(const uint4*)(row + lane * 8);
  float v[8];
  float m = -1e30f;
#pragma unroll
  for (int j = 0; j < 8; ++j) {
    unsigned int bi = ((unsigned int)io.us[j]) << 16;
    v[j] = (__builtin_bit_cast(float, bi) + ch[j]) * scale;
    m = fmaxf(m, v[j]);
  }
#pragma unroll
  for (int off = 32; off; off >>= 1) m = fmaxf(m, __shfl_xor(m, off, 64));
  float sum = 0.f;
#pragma unroll
  for (int j = 0; j < 8; ++j) { v[j] = __expf(v[j] - m); sum += v[j]; }
#pragma unroll
  for (int off = 32; off; off >>= 1) sum += __shfl_xor(sum, off, 64);
  const float rinv = 1.0f / sum;
#pragma unroll
  for (int j = 0; j < 8; ++j) io.us[j] = f2b(v[j] * rinv);
  *(uint4*)(row + lane * 8) = io.u;
}

extern "C" void kernel_launch(void* const* d_in, const int* in_sizes, int n_in,
                              void* d_out, int out_size, void* d_ws, size_t ws_size,
                              hipStream_t stream) {
  (void)in_sizes; (void)n_in;
  const float* X    = (const float*)d_in[0];  // [8192,512]
  const float* enc0 = (const float*)d_in[1];  // [512,8192]
  const float* enc1 = (const float*)d_in[2];  // [512,8192]
  const float* Wq   = (const float*)d_in[3];  // [8,512,512]
  const float* bq   = (const float*)d_in[4];  // [8,512]
  const float* Wc   = (const float*)d_in[5];  // [512,4096]
  const float* bc   = (const float*)d_in[6];  // [512]
  float* out = (float*)d_out;                 // [8192,512] f32

  const size_t NEED = 83902464;  // 80.02 MB
  if (ws_size < NEED) {
    zero_out_k<<<dim3((out_size + 255) / 256), 256, 0, stream>>>(out, out_size);
    return;
  }
  char* w = (char*)d_ws;
  // Ecat (64 MB, written by logits GEMM) overlays all transients below it.
  bfu*   Ecat  = (bfu*)(w + 0);           // [8192][4096] 64 MB
  bfu*   XTb   = (bfu*)(w + 0);           // [512][8192]   8 MB (transient)
  bfu*   enc0b = (bfu*)(w + 8388608);     // [512][8192]   8 MB (transient)
  bfu*   enc1b = (bfu*)(w + 16777216);    // [512][8192]   8 MB (transient)
  bfu*   WqTb  = (bfu*)(w + 25165824);    // [8][512][512] 4 MB (transient)
  bfu*   Wcb   = (bfu*)(w + 29360128);    // [512][4096]   4 MB (transient)
  float* K32   = (float*)(w + 33554432);  // [512][512]    1 MB (transient)
  float* V32   = (float*)(w + 34603008);  // [512][512]    1 MB (transient)
  bfu*   Kb    = (bfu*)(w + 35651584);    // [512][512]  0.5 MB (transient)
  bfu*   VTb   = (bfu*)(w + 36175872);    // [512][512]  0.5 MB (transient)
  bfu*   Xb    = (bfu*)(w + 67108864);    // [8192][512]   8 MB
  bfu*   Mb    = (bfu*)(w + 75497472);    // [8][512][512] 4 MB
  bfu*   Ncat  = (bfu*)(w + 79691776);    // [512][4096]   4 MB
  float* cb    = (float*)(w + 83886080);  // [8][512]     16 KB

  conv_mat<<<dim3(4096), 256, 0, stream>>>(X, Xb, 1048576);
  conv_mat<<<dim3(4096), 256, 0, stream>>>(enc0, enc0b, 1048576);
  conv_mat<<<dim3(4096), 256, 0, stream>>>(enc1, enc1b, 1048576);
  conv_mat<<<dim3(2048), 256, 0, stream>>>(Wc, Wcb, 524288);

  dim3 tb(32, 8, 1);
  transpose_k<<<dim3(16, 256, 1), tb, 0, stream>>>(X, XTb, 8192, 512);
  transpose_k<<<dim3(16, 16, 8), tb, 0, stream>>>(Wq, WqTb, 512, 512);

  zero_k<<<dim3(2048), 256, 0, stream>>>(K32);  // K32+V32 contiguous

  // K = enc0 @ X, V = enc1 @ X  (split-K over 16 chunks of 512; 512 blocks)
  gemm64<0><<<dim3(4, 8, 16), 256, 0, stream>>>(enc0b, XTb, K32, nullptr,
      8192, 8192, 512, 0, 0, 0, 512, 1);
  gemm64<0><<<dim3(4, 8, 16), 256, 0, stream>>>(enc1b, XTb, V32, nullptr,
      8192, 8192, 512, 0, 0, 0, 512, 1);
  cast_kv<<<dim3(1024), 256, 0, stream>>>(K32, V32, Kb, VTb);
  cvec_k<<<dim3(1024), 256, 0, stream>>>(K32, bq, cb);

  // M_h = K @ Wq_h
  gemm64<1><<<dim3(4, 8, 8), 256, 0, stream>>>(Kb, WqTb, Mb, nullptr,
      512, 512, 512, 0, 262144, 262144, 512, 0);
  // N_h = Wc_h @ V -> Ncat[o][h*512+a]
  gemm64<1><<<dim3(4, 8, 8), 256, 0, stream>>>(Wcb, VTb, Ncat, nullptr,
      4096, 512, 4096, 512, 0, 512, 512, 0);

  // logits_h = X @ M_h^T -> Ecat[s][h*512+a]  (4096 blocks, oversubscribed)
  gemm64<1><<<dim3(4, 128, 8), 256, 0, stream>>>(Xb, Mb, Ecat, nullptr,
      512, 512, 4096, 0, 262144, 512, 512, 0);
  softmax_k<<<dim3(16384), 256, 0, stream>>>(Ecat, cb);

  // out = Ecat @ Ncat^T + bc  (512 blocks = 2/CU, K=4096)
  gemm64<2><<<dim3(4, 128, 1), 256, 0, stream>>>(Ecat, Ncat, out, bc,
      4096, 4096, 512, 0, 0, 0, 4096, 0);
}